// Round 1
// baseline (464.211 us; speedup 1.0000x reference)
//
#include <hip/hip_runtime.h>
#include <hip/hip_bf16.h>

namespace {

constexpr int kB  = 8192;   // batch
constexpr int kH  = 1024;   // hidden
constexpr int kK  = 2048;   // H + I (concat dim)
constexpr int BM  = 128;    // batch rows per block
constexpr int BH  = 32;     // hidden cols per block
constexpr int BN  = 128;    // gate cols per block = 4 * BH
constexpr int BK  = 32;     // K step (one MFMA K)
constexpr int NKT = kK / BK;

typedef float f32x4 __attribute__((ext_vector_type(4)));
typedef unsigned short u16x8 __attribute__((ext_vector_type(8)));

__device__ __forceinline__ unsigned short f2bf(float f) {
  return __builtin_bit_cast(unsigned short, __float2bfloat16(f));
}

__device__ __forceinline__ float sigmoidf_(float x) {
  return 1.0f / (1.0f + __expf(-x));
}

// One block: 128 batch rows x 32 hidden cols, all 4 gates (128x128 gate tile).
// 256 threads = 4 waves; wave (wr,wc) owns a 64x64 quadrant, 4x4 frags of 16x16x32.
__global__ __launch_bounds__(256, 2) void sublstm_fused(
    const float* __restrict__ input,
    const float* __restrict__ weights,
    const float* __restrict__ bias,
    const float* __restrict__ old_h,
    const float* __restrict__ old_cell,
    float* __restrict__ out) {

  __shared__ unsigned short As[BM][BK + 8];   // +8 pad: row stride 80B -> <=2-way banks
  __shared__ unsigned short Bs[BN][BK + 8];
  __shared__ float Gc[32][BN + 4];            // epilogue gate exchange chunk

  const int tid  = threadIdx.x;
  const int lane = tid & 63;
  const int wid  = tid >> 6;
  const int wr   = wid >> 1;   // 0..1 row half
  const int wc   = wid & 1;    // 0..1 col half

  const int bid = blockIdx.x;
  const int bm  = bid & 63;         // batch-row block (64 consecutive bids share weights panel)
  const int hh0 = (bid >> 6) * BH;  // hidden block base

  // ---- staging map: 2 threads per tile row, 16 consecutive floats each ----
  const int ra = tid >> 1;            // tile row 0..127 (A: batch row; B: gate row)
  const int ca = (tid & 1) << 4;      // 0 or 16
  const long arow = (long)bm * BM + ra;
  const int  wrow = (ra >> 5) * kH + hh0 + (ra & 31);  // gate (ra>>5), hidden col

  const float* abase_h = old_h + arow * kH + ca;        // valid for k0 < kH
  const float* abase_x = input + arow * kH + ca - kH;   // valid for k0 >= kH
  const float* wbase   = weights + (long)wrow * kK + ca;

  // ---- MFMA fragment map (16x16x32 bf16, B^T convention) ----
  const int fr = lane & 15;          // A row / B col within fragment
  const int ks = (lane >> 4) << 3;   // k chunk: 0,8,16,24

  f32x4 acc[4][4];
  #pragma unroll
  for (int m = 0; m < 4; ++m)
    #pragma unroll
    for (int n = 0; n < 4; ++n)
      acc[m][n] = f32x4{0.f, 0.f, 0.f, 0.f};

  // prologue: load k-tile 0 into registers
  float4 a0, a1, a2, a3, b0, b1, b2, b3;
  {
    const float4* ap4 = reinterpret_cast<const float4*>(abase_h);
    const float4* wp4 = reinterpret_cast<const float4*>(wbase);
    a0 = ap4[0]; a1 = ap4[1]; a2 = ap4[2]; a3 = ap4[3];
    b0 = wp4[0]; b1 = wp4[1]; b2 = wp4[2]; b3 = wp4[3];
  }

  for (int kt = 0; kt < NKT; ++kt) {
    // convert current k-tile regs -> bf16 packs
    u16x8 pa0 = { f2bf(a0.x), f2bf(a0.y), f2bf(a0.z), f2bf(a0.w),
                  f2bf(a1.x), f2bf(a1.y), f2bf(a1.z), f2bf(a1.w) };
    u16x8 pa1 = { f2bf(a2.x), f2bf(a2.y), f2bf(a2.z), f2bf(a2.w),
                  f2bf(a3.x), f2bf(a3.y), f2bf(a3.z), f2bf(a3.w) };
    u16x8 pb0 = { f2bf(b0.x), f2bf(b0.y), f2bf(b0.z), f2bf(b0.w),
                  f2bf(b1.x), f2bf(b1.y), f2bf(b1.z), f2bf(b1.w) };
    u16x8 pb1 = { f2bf(b2.x), f2bf(b2.y), f2bf(b2.z), f2bf(b2.w),
                  f2bf(b3.x), f2bf(b3.y), f2bf(b3.z), f2bf(b3.w) };

    __syncthreads();  // previous iteration's ds_reads are complete
    *reinterpret_cast<u16x8*>(&As[ra][ca])     = pa0;
    *reinterpret_cast<u16x8*>(&As[ra][ca + 8]) = pa1;
    *reinterpret_cast<u16x8*>(&Bs[ra][ca])     = pb0;
    *reinterpret_cast<u16x8*>(&Bs[ra][ca + 8]) = pb1;
    __syncthreads();

    // issue next k-tile global loads early (latency hides under MFMAs)
    if (kt + 1 < NKT) {
      const int k0n = (kt + 1) * BK;
      const float* ap = (k0n < kH) ? (abase_h + k0n) : (abase_x + k0n);
      const float4* ap4 = reinterpret_cast<const float4*>(ap);
      const float4* wp4 = reinterpret_cast<const float4*>(wbase + k0n);
      a0 = ap4[0]; a1 = ap4[1]; a2 = ap4[2]; a3 = ap4[3];
      b0 = wp4[0]; b1 = wp4[1]; b2 = wp4[2]; b3 = wp4[3];
    }

    u16x8 af[4], bfr[4];
    #pragma unroll
    for (int m = 0; m < 4; ++m)
      af[m] = *reinterpret_cast<const u16x8*>(&As[wr * 64 + m * 16 + fr][ks]);
    #pragma unroll
    for (int n = 0; n < 4; ++n)
      bfr[n] = *reinterpret_cast<const u16x8*>(&Bs[wc * 64 + n * 16 + fr][ks]);

    #pragma unroll
    for (int m = 0; m < 4; ++m)
      #pragma unroll
      for (int n = 0; n < 4; ++n)
        asm("v_mfma_f32_16x16x32_bf16 %0, %1, %2, %0"
            : "+v"(acc[m][n]) : "v"(af[m]), "v"(bfr[n]));
  }

  // ---- fused epilogue: exchange gates through LDS in 4 row-chunks ----
  float* out_h = out;
  float* out_c = out + (long)kB * kH;

  #pragma unroll
  for (int m = 0; m < 4; ++m) {
    __syncthreads();  // previous chunk fully consumed
    #pragma unroll
    for (int n = 0; n < 4; ++n) {
      const int col = wc * 64 + n * 16 + fr;      // C/D: col = lane&15
      #pragma unroll
      for (int j = 0; j < 4; ++j)
        Gc[wr * 16 + (lane >> 4) * 4 + j][col] = acc[m][n][j];  // row=(lane>>4)*4+j
    }
    __syncthreads();

    // 32 rows x 32 hidden = 1024 outputs; 4 per thread
    #pragma unroll
    for (int q = 0; q < 4; ++q) {
      const int idx = tid + (q << 8);
      const int r = idx >> 5;        // chunk row 0..31
      const int h = idx & 31;        // hidden col 0..31
      const int hg = hh0 + h;
      const float gi = sigmoidf_(Gc[r][h]      + bias[hg]);
      const float go = sigmoidf_(Gc[r][32 + h] + bias[kH + hg]);
      const float gz = sigmoidf_(Gc[r][64 + h] + bias[2 * kH + hg]);
      const float gf = sigmoidf_(Gc[r][96 + h] + bias[3 * kH + hg]);
      const int grow = bm * BM + (r >> 4) * 64 + m * 16 + (r & 15);
      const long off = (long)grow * kH + hg;
      const float oc = old_cell[off];
      const float nc = oc * gf + gz - gi;
      out_h[off] = sigmoidf_(nc) - go;
      out_c[off] = nc;
    }
  }
}

}  // namespace

extern "C" void kernel_launch(void* const* d_in, const int* in_sizes, int n_in,
                              void* d_out, int out_size, void* d_ws, size_t ws_size,
                              hipStream_t stream) {
  const float* input    = (const float*)d_in[0];
  const float* weights  = (const float*)d_in[1];
  const float* bias     = (const float*)d_in[2];
  const float* old_h    = (const float*)d_in[3];
  const float* old_cell = (const float*)d_in[4];
  float* out = (float*)d_out;

  const int grid = (kB / BM) * (kH / BH);  // 64 * 32 = 2048
  sublstm_fused<<<dim3(grid), dim3(256), 0, stream>>>(
      input, weights, bias, old_h, old_cell, out);
}